// Round 5
// baseline (282.656 us; speedup 1.0000x reference)
//
#include <hip/hip_runtime.h>

// ConditionalFeedForward (gpt-fast MoE FFN), MI355X. fp32 in/out.
//   x[T][H], idx[T][K], gate[E][I][H], up[E][H][I], down[E][I][H]
//   hbuf[p][o] = silu(x.gate_row)*(x.down_row);  out[p][h] = hbuf[p].up_row
// R4 evidence: latency-bound on per-pair serial chains (VALUBusy 13.5%,
// occupancy-doubling neutral, HBM-vs-L3 source neutral). R5: batch pairs in
// compile-time chunks -> independent x-loads + interleaved butterfly trees.
#define NE 8
#define HD 1024
#define IW 2816
#define NT 16
#define TK 2
#define NP (NT*TK)

// Phase 1: one wave per (expert, o-row); pairs processed 4 at a time with
// all x-loads in flight and 8 reduction trees interleaved.
__global__ __launch_bounds__(256) void moe_phase1(
    const float* __restrict__ x,      // [NT][HD]
    const int*   __restrict__ idx,    // [NT][TK]
    const float* __restrict__ gate,   // [NE][IW][HD]
    const float* __restrict__ down,   // [NE][IW][HD]
    float*       __restrict__ hbuf)   // [NP][IW]
{
    __shared__ int s_list[NP];
    __shared__ int s_n;
    const int e = blockIdx.y;
    if (threadIdx.x == 0) {
        int n = 0;
        for (int p = 0; p < NP; ++p) if (idx[p] == e) s_list[n++] = p;
        s_n = n;
    }
    __syncthreads();
    const int npl = s_n;
    if (npl == 0) return;

    const int wave = threadIdx.x >> 6;
    const int lane = threadIdx.x & 63;
    const int o = blockIdx.x * 4 + wave;          // gridDim.x = IW/4

    const float* grow = gate + ((size_t)e * IW + o) * HD + lane * 4;
    const float* drow = down + ((size_t)e * IW + o) * HD + lane * 4;
    float4 gw[4], dw[4];
    #pragma unroll
    for (int c = 0; c < 4; ++c) {                  // HD = 4*256
        gw[c] = *(const float4*)(grow + c * 256);
        dw[c] = *(const float4*)(drow + c * 256);
    }

    for (int base = 0; base < npl; base += 4) {
        // 4 pairs per chunk (clamped duplicates are benign rewrites)
        float4 xv[4][4];
        #pragma unroll
        for (int j = 0; j < 4; ++j) {
            int bj = base + j; if (bj >= npl) bj = npl - 1;
            const float* xr = x + (size_t)(s_list[bj] >> 1) * HD + lane * 4;
            #pragma unroll
            for (int c = 0; c < 4; ++c) xv[j][c] = *(const float4*)(xr + c * 256);
        }
        float ag[4] = {0,0,0,0}, ad[4] = {0,0,0,0};
        #pragma unroll
        for (int j = 0; j < 4; ++j) {
            #pragma unroll
            for (int c = 0; c < 4; ++c) {
                float4 xc = xv[j][c];
                ag[j] += xc.x*gw[c].x + xc.y*gw[c].y + xc.z*gw[c].z + xc.w*gw[c].w;
                ad[j] += xc.x*dw[c].x + xc.y*dw[c].y + xc.z*dw[c].z + xc.w*dw[c].w;
            }
        }
        // 8 independent butterfly trees, interleaved by the scheduler
        #pragma unroll
        for (int off = 32; off > 0; off >>= 1) {
            #pragma unroll
            for (int j = 0; j < 4; ++j) {
                ag[j] += __shfl_xor(ag[j], off, 64);
                ad[j] += __shfl_xor(ad[j], off, 64);
            }
        }
        if (lane < 4) {
            // select this lane's pair without dynamic register indexing
            float a = (lane == 0) ? ag[0] : (lane == 1) ? ag[1] : (lane == 2) ? ag[2] : ag[3];
            float d = (lane == 0) ? ad[0] : (lane == 1) ? ad[1] : (lane == 2) ? ad[2] : ad[3];
            int bj = base + lane; if (bj >= npl) bj = npl - 1;
            float s = a / (1.f + __expf(-a));     // silu
            hbuf[(size_t)s_list[bj] * IW + o] = s * d;
        }
    }
}

// Phase 2: one wave per (expert, h-row); pairs processed 2 at a time with
// both hbuf row streams in flight and 2 reduction trees interleaved.
__global__ __launch_bounds__(256) void moe_phase2(
    const float* __restrict__ up,     // [NE][HD][IW]
    const int*   __restrict__ idx,
    const float* __restrict__ hbuf,   // [NP][IW]
    float*       __restrict__ out)    // [NP][HD]
{
    __shared__ int s_list[NP];
    __shared__ int s_n;
    const int e = blockIdx.y;
    if (threadIdx.x == 0) {
        int n = 0;
        for (int p = 0; p < NP; ++p) if (idx[p] == e) s_list[n++] = p;
        s_n = n;
    }
    __syncthreads();
    const int npl = s_n;
    if (npl == 0) return;

    const int wave = threadIdx.x >> 6;
    const int lane = threadIdx.x & 63;
    const int h = blockIdx.x * 4 + wave;          // gridDim.x = HD/4

    const float* urow = up + ((size_t)e * HD + h) * IW + lane * 4;
    float4 w[11];                                  // IW = 11*256
    #pragma unroll
    for (int c = 0; c < 11; ++c) w[c] = *(const float4*)(urow + c * 256);

    for (int base = 0; base < npl; base += 2) {
        int b0 = base, b1 = base + 1; if (b1 >= npl) b1 = npl - 1;
        const float* h0 = hbuf + (size_t)s_list[b0] * IW + lane * 4;
        const float* h1 = hbuf + (size_t)s_list[b1] * IW + lane * 4;
        float a0 = 0.f, a1 = 0.f;
        #pragma unroll
        for (int c = 0; c < 11; ++c) {
            float4 v0 = *(const float4*)(h0 + c * 256);
            float4 v1 = *(const float4*)(h1 + c * 256);
            a0 += w[c].x*v0.x + w[c].y*v0.y + w[c].z*v0.z + w[c].w*v0.w;
            a1 += w[c].x*v1.x + w[c].y*v1.y + w[c].z*v1.z + w[c].w*v1.w;
        }
        #pragma unroll
        for (int off = 32; off > 0; off >>= 1) {
            a0 += __shfl_xor(a0, off, 64);
            a1 += __shfl_xor(a1, off, 64);
        }
        if (lane < 2) {
            float a = (lane == 0) ? a0 : a1;
            int bj = base + lane; if (bj >= npl) bj = npl - 1;
            out[(size_t)s_list[bj] * HD + h] = a;
        }
    }
}

extern "C" void kernel_launch(void* const* d_in, const int* in_sizes, int n_in,
                              void* d_out, int out_size, void* d_ws, size_t ws_size,
                              hipStream_t stream) {
    const float* x    = (const float*)d_in[0];
    const int*   idx  = (const int*)  d_in[1];
    const float* gate = (const float*)d_in[2];
    const float* up   = (const float*)d_in[3];
    const float* down = (const float*)d_in[4];
    float* hbuf = (float*)d_ws;              // 32*2816*4 = 360448 B scratch
    float* out  = (float*)d_out;             // [16][2][1024]

    moe_phase1<<<dim3(IW/4, NE), dim3(256), 0, stream>>>(x, idx, gate, down, hbuf);
    moe_phase2<<<dim3(HD/4, NE), dim3(256), 0, stream>>>(up, idx, hbuf, out);
}